// Round 15
// baseline (386.525 us; speedup 1.0000x reference)
//
#include <hip/hip_runtime.h>

typedef unsigned short u16;
typedef unsigned int u32;
typedef __bf16 bf16x8 __attribute__((ext_vector_type(8)));
typedef float f32x4 __attribute__((ext_vector_type(4)));
typedef float f32x16 __attribute__((ext_vector_type(16)));

__device__ __forceinline__ float b2f(u16 u) { return __uint_as_float(((u32)u) << 16); }
__device__ __forceinline__ u16 f2b(float f) {
  u32 u = __float_as_uint(f);
  u += 0x7fffu + ((u >> 16) & 1u);   // round-to-nearest-even
  return (u16)(u >> 16);
}

// async global->LDS, 16B per lane; lds dest = wave-uniform base + lane*16
__device__ __forceinline__ void gll16(const u16* g, u16* l) {
  __builtin_amdgcn_global_load_lds(
      (const __attribute__((address_space(1))) void*)g,
      (__attribute__((address_space(3))) void*)l, 16, 0, 0);
}

// load 4 consecutive elements, dtype-polymorphic (uniform branch)
__device__ __forceinline__ float4 load4(const void* p, size_t idx, bool f32) {
  if (f32) return *(const float4*)((const float*)p + idx);
  ushort4 u = *(const ushort4*)((const u16*)p + idx);
  return make_float4(b2f(u.x), b2f(u.y), b2f(u.z), b2f(u.w));
}

#define SB __builtin_amdgcn_sched_barrier(0)
#define BARRIER do { SB; __builtin_amdgcn_s_barrier(); SB; } while (0)

// ---------------------------------------------------------------- dtype sniff (device-side, proven)
__global__ __launch_bounds__(256) void detect_kernel(const u16* __restrict__ sig,
                                                     int* __restrict__ flag) {
  __shared__ int cnt;
  if (threadIdx.x == 0) cnt = 0;
  __syncthreads();
  int c = 0;
  for (int i = threadIdx.x; i < 16384; i += 256) {
    u16 v = sig[i];
    c += ((v & 0x7F80u) == 0x7F80u) ? 1 : 0;
  }
  atomicAdd(&cnt, c);
  __syncthreads();
  if (threadIdx.x == 0) *flag = (cnt >= 8) ? 1 : 0;
}

// ---------------------------------------------------------------- prep (LN + weight prep, fused dispatch)
__global__ __launch_bounds__(256) void prep_kernel(
    const int* __restrict__ flag,
    const void* __restrict__ mu, const void* __restrict__ sigma,
    const void* __restrict__ gamma, const void* __restrict__ beta,
    u16* __restrict__ mu_n, u16* __restrict__ a1sg,
    const void* __restrict__ wq_mu, const void* __restrict__ wq_sraw,
    u16* __restrict__ q_bf, u16* __restrict__ q_s2,
    const void* __restrict__ wo_mu, const void* __restrict__ wo_sraw,
    u16* __restrict__ o_bf, u16* __restrict__ o_s2)
{
  __shared__ float ps[4], pq[4];
  const bool f32 = (*flag != 0);
  const int t = threadIdx.x;

  if (blockIdx.x < 4096) {
    const int wv = t >> 6, lane = t & 63;
    const size_t base = (size_t)blockIdx.x * 1024 + (size_t)t * 4;
    float4 xm = load4(mu, base, f32);
    float4 xs = load4(sigma, base, f32);
    float x0 = xm.x, x1 = xm.y, x2 = xm.z, x3 = xm.w;
    float s0 = xs.x, s1 = xs.y, s2 = xs.z, s3 = xs.w;

    float sv = x0 + x1 + x2 + x3;
    float qv = x0*x0 + x1*x1 + x2*x2 + x3*x3;
    #pragma unroll
    for (int off = 32; off > 0; off >>= 1) {
      sv += __shfl_xor(sv, off, 64);
      qv += __shfl_xor(qv, off, 64);
    }
    if (lane == 0) { ps[wv] = sv; pq[wv] = qv; }
    __syncthreads();
    float sum = ps[0] + ps[1] + ps[2] + ps[3];
    float ssq = pq[0] + pq[1] + pq[2] + pq[3];

    float mean = sum * (1.0f / 1024.0f);
    float var  = ssq * (1.0f / 1024.0f) - mean * mean;
    float inv  = 1.0f / sqrtf(var + 1e-5f);
    float inv2 = inv * inv;

    float4 g4 = load4(gamma, (size_t)t * 4, f32);
    float4 b4 = load4(beta, (size_t)t * 4, f32);

    float m0 = (x0 - mean) * inv * g4.x + b4.x;
    float m1 = (x1 - mean) * inv * g4.y + b4.y;
    float m2 = (x2 - mean) * inv * g4.z + b4.z;
    float m3 = (x3 - mean) * inv * g4.w + b4.w;
    float v0 = s0 * g4.x * g4.x * inv2;
    float v1 = s1 * g4.y * g4.y * inv2;
    float v2 = s2 * g4.z * g4.z * inv2;
    float v3 = s3 * g4.w * g4.w * inv2;

    ushort4 omu = { f2b(m0), f2b(m1), f2b(m2), f2b(m3) };
    ushort4 oa1 = { f2b(m0*m0 + v0), f2b(m1*m1 + v1), f2b(m2*m2 + v2), f2b(m3*m3 + v3) };
    ushort4 osg = { f2b(v0), f2b(v1), f2b(v2), f2b(v3) };
    *(ushort4*)(mu_n + base) = omu;
    size_t r2 = (size_t)blockIdx.x * 2048 + (size_t)t * 4;
    *(ushort4*)(a1sg + r2) = oa1;
    *(ushort4*)(a1sg + r2 + 1024) = osg;
  } else {
    const int nq = 3072 * 1024;
    size_t idx = ((size_t)(blockIdx.x - 4096) * 256 + t) * 4;
    const void *wmu, *wsr; u16 *obf, *os2;
    if (idx < (size_t)nq) { wmu = wq_mu; wsr = wq_sraw; obf = q_bf; os2 = q_s2; }
    else { idx -= nq; wmu = wo_mu; wsr = wo_sraw; obf = o_bf; os2 = o_s2; }
    int row = (int)(idx >> 10), k = (int)(idx & 1023);
    float4 m4 = load4(wmu, idx, f32);
    float4 s4 = load4(wsr, idx, f32);
    float m[4] = { m4.x, m4.y, m4.z, m4.w };
    float s[4] = { s4.x, s4.y, s4.z, s4.w };
    ushort4 ob, os, oq;
    u16* obp = (u16*)&ob; u16* osp = (u16*)&os; u16* oqp = (u16*)&oq;
    #pragma unroll
    for (int i = 0; i < 4; ++i) {
      float sp = (s[i] > 15.f) ? s[i] : log1pf(__expf(s[i]));
      obp[i] = f2b(m[i]);
      osp[i] = f2b(sp);
      oqp[i] = f2b(m[i] * m[i]);
    }
    *(ushort4*)(obf + idx) = ob;
    size_t r2 = (size_t)row * 2048 + k;
    *(ushort4*)(os2 + r2) = os;
    *(ushort4*)(os2 + r2 + 1024) = oq;
  }
}

// ---------------------------------------------------------------- out GEMM (64x64 tiles, drain, XCD-affine, 8 blocks/CU)
// Occupancy lever, fourth pull (2->4: -9us, 4->6: -13us): 16KB LDS, 2048
// blocks, __launch_bounds__(256,8). Spill tripwire: WRITE_SIZE balloon ->
// revert to (256,6).
template<bool DYN>
__global__ __launch_bounds__(256, 8) void gemm_out_kernel(
    const u16* __restrict__ A0, const u16* __restrict__ B0, int K0, void* C0, size_t ob0,
    const u16* __restrict__ A1, const u16* __restrict__ B1, int K1, void* C1, size_t ob1,
    int N, const int* __restrict__ flag)
{
  __shared__ u16 lA[64 * 64];
  __shared__ u16 lB[64 * 64];
  const int t = threadIdx.x;

  const int wgid = blockIdx.x;          // 2048
  const int xcd = wgid & 7;
  const int idx = wgid >> 3;            // 0..255 per XCD
  const u16 *A, *B; void* C; size_t obase; int K; int l;
  if (idx < 128) { A = A0; B = B0; K = K0; C = C0; obase = ob0; l = idx; }
  else           { A = A1; B = B1; K = K1; C = C1; obase = ob1; l = idx - 128; }
  const int by = xcd * 8 + (l >> 4);    // 0..63  (64 m-panels of 64 rows)
  const int bx = l & 15;                // 0..15  (16 n-tiles of 64 cols)
  const int n0 = bx * 64, m0 = by * 64;

  const int lane = t & 63, wave = t >> 6;
  const int wr = (wave >> 1) * 32, wc = (wave & 1) * 32;
  const int m31 = lane & 31, h5 = lane >> 5;
  const int mx = m31 & 7;

  const int srow = t >> 3;              // 0..31
  const int gseg = (t & 7) ^ (srow & 7);

  f32x16 acc;
  #pragma unroll
  for (int r = 0; r < 16; ++r) acc[r] = 0.f;

  for (int k0 = 0; k0 < K; k0 += 64) {
    __syncthreads();
    #pragma unroll
    for (int rep = 0; rep < 2; ++rep) {
      gll16(A + (size_t)(m0 + srow + rep * 32) * K + k0 + gseg * 8,
            lA + rep * 2048 + wave * 512);
      gll16(B + (size_t)(n0 + srow + rep * 32) * K + k0 + gseg * 8,
            lB + rep * 2048 + wave * 512);
    }
    __syncthreads();
    #pragma unroll
    for (int ks = 0; ks < 4; ++ks) {
      const int seg = ks * 2 + h5;
      bf16x8 af = *(const bf16x8*)&lA[(wr + m31) * 64 + (seg ^ mx) * 8];
      bf16x8 bfr = *(const bf16x8*)&lB[(wc + m31) * 64 + (seg ^ mx) * 8];
      acc = __builtin_amdgcn_mfma_f32_32x32x16_bf16(af, bfr, acc, 0, 0, 0);
    }
  }

  const bool of32 = DYN && (*flag != 0);
  {
    int colb = n0 + wc + m31;
    #pragma unroll
    for (int r = 0; r < 16; ++r) {
      int row = m0 + wr + (r & 3) + 8 * (r >> 2) + 4 * h5;
      float v = acc[r];
      size_t off = obase + (size_t)row * N + colb;
      if (DYN) {
        if (of32) ((float*)C)[off] = v;
        else      ((u16*)C)[off] = f2b(v);
      } else {
        ((u16*)C)[off] = f2b(v);
      }
    }
  }
}

// ---------------------------------------------------------------- paired GEMM (256^2, 8-phase counted-vmcnt, 32x32 MFMA)
// R3/R9-measured version (109.5 us on QKV).
__global__ __launch_bounds__(512, 2) void gemm8_pair_kernel(
    const u16* __restrict__ A0, const u16* __restrict__ B0, int K0, u16* __restrict__ C0,
    const u16* __restrict__ A1, const u16* __restrict__ B1, int K1, u16* __restrict__ C1,
    int split, int N)
{
  __shared__ u16 lA[2 * 256 * 64];
  __shared__ u16 lB[2 * 256 * 64];
  const int t = threadIdx.x;

  int wgid = blockIdx.y * 24 + blockIdx.x;     // 384 total; 192 per class
  int job;
  if (wgid < 192) job = (wgid & 7) * 24 + (wgid >> 3);
  else { int w2 = wgid - 192; job = 192 + (w2 & 7) * 24 + (w2 >> 3); }

  const u16 *A, *B; u16* C; int K, jb;
  if (job < split) { A = A0; B = B0; K = K0; C = C0; jb = job; }
  else { A = A1; B = B1; K = K1; C = C1; jb = job - split; }
  const int bm = jb & 15, bn = jb >> 4;        // 16 m-tiles x 12 n-tiles
  const int m0 = bm * 256, n0 = bn * 256;
  const int NT = K >> 6;

  const int lane = t & 63, wave = t >> 6;
  const int wm = wave >> 2, wn = wave & 3;
  const int m31 = lane & 31, h5 = lane >> 5, mx = m31 & 7;

  auto stg64 = [&](const u16* __restrict__ X, int row0, int k0, u16* ldsU) {
    int r = row0 + wave * 8 + (lane >> 3);
    int seg = (lane & 7) ^ ((lane >> 3) & 7);
    gll16(X + (size_t)r * K + k0 + seg * 8, ldsU + wave * 512);
  };

  const u16* rdA = lA + (wm * 128 + m31) * 64;
  const u16* rdB = lB + (wn * 64 + m31) * 64;

  f32x16 acc[4][2];
  #pragma unroll
  for (int i = 0; i < 4; ++i)
    #pragma unroll
    for (int j = 0; j < 2; ++j)
      #pragma unroll
      for (int r = 0; r < 16; ++r) acc[i][j][r] = 0.f;

  bf16x8 af[2][4];
  bf16x8 bf[2][4];

  #pragma unroll
  for (int u = 0; u < 4; ++u) stg64(A, m0 + u * 64, 0, lA + u * 4096);
  #pragma unroll
  for (int u = 0; u < 4; ++u) stg64(B, n0 + u * 64, 0, lB + u * 4096);
  if (NT > 1) {
    #pragma unroll
    for (int u = 0; u < 4; ++u) stg64(B, n0 + u * 64, 64, lB + 16384 + u * 4096);
  }
  SB;
  asm volatile("s_waitcnt vmcnt(4)" ::: "memory");
  BARRIER;

  for (int T = 0; T < NT; ++T) {
    const int bo  = (T & 1) * 16384;
    const int bon = bo ^ 16384;
    const int kn  = (T + 1) * 64;
    const int kn2 = (T + 2) * 64;

    // -------- P1
    #pragma unroll
    for (int mf = 0; mf < 2; ++mf)
      #pragma unroll
      for (int ks = 0; ks < 4; ++ks)
        af[mf][ks] = *(const bf16x8*)&rdA[bo + mf * 2048 + (((ks * 2 + h5)) ^ mx) * 8];
    #pragma unroll
    for (int ks = 0; ks < 4; ++ks)
      bf[0][ks] = *(const bf16x8*)&rdB[bo + (((ks * 2 + h5)) ^ mx) * 8];
    if (T + 1 < NT) {
      stg64(A, m0,      kn, lA + bon);
      stg64(A, m0 + 64, kn, lA + bon + 4096);
    }
    BARRIER;
    __builtin_amdgcn_s_setprio(1);
    #pragma unroll
    for (int mf = 0; mf < 2; ++mf)
      #pragma unroll
      for (int ks = 0; ks < 4; ++ks)
        acc[mf][0] = __builtin_amdgcn_mfma_f32_32x32x16_bf16(af[mf][ks], bf[0][ks], acc[mf][0], 0, 0, 0);
    __builtin_amdgcn_s_setprio(0);
    BARRIER;

    // -------- P2
    #pragma unroll
    for (int ks = 0; ks < 4; ++ks)
      bf[1][ks] = *(const bf16x8*)&rdB[bo + 2048 + (((ks * 2 + h5)) ^ mx) * 8];
    if (T + 1 < NT) {
      stg64(A, m0 + 128, kn, lA + bon + 8192);
      stg64(A, m0 + 192, kn, lA + bon + 12288);
    }
    BARRIER;
    __builtin_amdgcn_s_setprio(1);
    #pragma unroll
    for (int mf = 0; mf < 2; ++mf)
      #pragma unroll
      for (int ks = 0; ks < 4; ++ks)
        acc[mf][1] = __builtin_amdgcn_mfma_f32_32x32x16_bf16(af[mf][ks], bf[1][ks], acc[mf][1], 0, 0, 0);
    __builtin_amdgcn_s_setprio(0);
    BARRIER;

    // -------- P3
    #pragma unroll
    for (int mf = 0; mf < 2; ++mf)
      #pragma unroll
      for (int ks = 0; ks < 4; ++ks)
        af[mf][ks] = *(const bf16x8*)&rdA[bo + (2 + mf) * 2048 + (((ks * 2 + h5)) ^ mx) * 8];
    if (T + 2 < NT) {
      stg64(B, n0,      kn2, lB + bo);
      stg64(B, n0 + 64, kn2, lB + bo + 4096);
    }
    BARRIER;
    __builtin_amdgcn_s_setprio(1);
    #pragma unroll
    for (int mf = 0; mf < 2; ++mf)
      #pragma unroll
      for (int ks = 0; ks < 4; ++ks)
        acc[2 + mf][1] = __builtin_amdgcn_mfma_f32_32x32x16_bf16(af[mf][ks], bf[1][ks], acc[2 + mf][1], 0, 0, 0);
    __builtin_amdgcn_s_setprio(0);
    BARRIER;

    // -------- P4
    if (T + 2 < NT) {
      stg64(B, n0 + 128, kn2, lB + bo + 8192);
      stg64(B, n0 + 192, kn2, lB + bo + 12288);
    }
    BARRIER;
    __builtin_amdgcn_s_setprio(1);
    #pragma unroll
    for (int mf = 0; mf < 2; ++mf)
      #pragma unroll
      for (int ks = 0; ks < 4; ++ks)
        acc[2 + mf][0] = __builtin_amdgcn_mfma_f32_32x32x16_bf16(af[mf][ks], bf[0][ks], acc[2 + mf][0], 0, 0, 0);
    __builtin_amdgcn_s_setprio(0);
    SB;
    if (T + 2 < NT) asm volatile("s_waitcnt vmcnt(4)" ::: "memory");
    else            asm volatile("s_waitcnt vmcnt(0)" ::: "memory");
    BARRIER;
  }

  #pragma unroll
  for (int mf = 0; mf < 4; ++mf)
    #pragma unroll
    for (int nf = 0; nf < 2; ++nf) {
      int colb = n0 + wn * 64 + nf * 32 + m31;
      #pragma unroll
      for (int r = 0; r < 16; ++r) {
        int row = m0 + wm * 128 + mf * 32 + (r & 3) + 8 * (r >> 2) + 4 * h5;
        C[(size_t)row * N + colb] = f2b(acc[mf][nf][r]);
      }
    }
}

// ---------------------------------------------------------------- fused attention (single pass, XCD-affine, T5 setprio)
// R11/R12-measured 111us body (2 barriers/tile, in-register a3 = ap (.) aw).
__global__ __launch_bounds__(512, 4) void attn_pass2f(
    const u16* __restrict__ qkv_mu, const u16* __restrict__ qkv_sg,
    u16* __restrict__ o_mu, u16* __restrict__ a1sgo)
{
  __shared__ u16 lKW[128 * 72];   // K-mu | K-sg
  __shared__ u16 lV[128 * 72];    // V-mu | V-sg (transposed)
  __shared__ u16 lP[128 * 72];    // e (unnormalized p)
  __shared__ u16 lW[128 * 72];    // e^2 * ss~

  const int t = threadIdx.x;
  const int wv = t >> 6, lane = t & 63;
  const int ml = lane & 15, qd = lane >> 4;
  const int bid = blockIdx.x;
  const int ib = (bid >> 3) & 7;
  const int bh = (bid & 7) + ((bid >> 6) << 3);
  const int b = bh >> 4, h = bh & 15;
  const size_t rowbase = (size_t)b * 1024 * 3072;
  const int i0 = ib * 128;
  const int qcol = h * 64, kcol = 1024 + h * 64, vcol = 2048 + h * 64;
  const int qrow = wv * 16;

  bf16x8 aQm[2], aQs[2];
  #pragma unroll
  for (int ks = 0; ks < 2; ++ks) {
    size_t ga = rowbase + (size_t)(i0 + qrow + ml) * 3072 + qcol + ks * 32 + qd * 8;
    aQm[ks] = *(const bf16x8*)(qkv_mu + ga);
    aQs[ks] = *(const bf16x8*)(qkv_sg + ga);
  }

  float lsum[4] = {0.f, 0.f, 0.f, 0.f};
  f32x4 accm[4], acc2[4], acc3[4];
  #pragma unroll
  for (int tj = 0; tj < 4; ++tj) {
    accm[tj] = (f32x4){0.f, 0.f, 0.f, 0.f};
    acc2[tj] = (f32x4){0.f, 0.f, 0.f, 0.f};
    acc3[tj] = (f32x4){0.f, 0.f, 0.f, 0.f};
  }

  for (int j0 = 0; j0 < 1024; j0 += 64) {
    __syncthreads();   // barA: prev-tile PV reads done before restaging
    #pragma unroll
    for (int rep = 0; rep < 2; ++rep) {
      int c = t + rep * 512;
      int row = c >> 3, seg = c & 7;
      const u16* src = (row < 64) ? qkv_mu : qkv_sg;
      int rr = row & 63;
      *(uint4*)&lKW[row * 72 + seg * 8] =
          *(const uint4*)(src + rowbase + (size_t)(j0 + rr) * 3072 + kcol + seg * 8);
    }
    {
      int buf = t >> 8, rem = t & 255;
      int db = rem >> 4, tb = rem & 15;
      const u16* src = buf ? qkv_sg : qkv_mu;
      ushort4 vals[4];
      #pragma unroll
      for (int i = 0; i < 4; ++i)
        vals[i] = *(const ushort4*)(src + rowbase + (size_t)(j0 + tb * 4 + i) * 3072 + vcol + db * 4);
      #pragma unroll
      for (int k = 0; k < 4; ++k) {
        ushort4 o;
        u16* op = (u16*)&o;
        const u16* v0 = (const u16*)&vals[0];
        const u16* v1 = (const u16*)&vals[1];
        const u16* v2 = (const u16*)&vals[2];
        const u16* v3 = (const u16*)&vals[3];
        op[0] = v0[k]; op[1] = v1[k]; op[2] = v2[k]; op[3] = v3[k];
        *(ushort4*)&lV[(buf * 64 + db * 4 + k) * 72 + tb * 4] = o;
      }
    }
    __syncthreads();   // barB: staging visible

    #pragma unroll
    for (int tj = 0; tj < 4; ++tj) {
      bf16x8 bm0 = *(const bf16x8*)&lKW[(tj * 16 + ml) * 72 + qd * 8];
      bf16x8 bm1 = *(const bf16x8*)&lKW[(tj * 16 + ml) * 72 + 32 + qd * 8];
      bf16x8 bs0 = *(const bf16x8*)&lKW[(64 + tj * 16 + ml) * 72 + qd * 8];
      bf16x8 bs1 = *(const bf16x8*)&lKW[(64 + tj * 16 + ml) * 72 + 32 + qd * 8];
      __builtin_amdgcn_s_setprio(1);
      f32x4 s = (f32x4){0.f, 0.f, 0.f, 0.f};
      s = __builtin_amdgcn_mfma_f32_16x16x32_bf16(aQm[0], bm0, s, 0, 0, 0);
      s = __builtin_amdgcn_mfma_f32_16x16x32_bf16(aQm[1], bm1, s, 0, 0, 0);
      f32x4 s2 = (f32x4){0.f, 0.f, 0.f, 0.f};
      s2 = __builtin_amdgcn_mfma_f32_16x16x32_bf16(aQs[0], bs0, s2, 0, 0, 0);
      s2 = __builtin_amdgcn_mfma_f32_16x16x32_bf16(aQs[1], bs1, s2, 0, 0, 0);
      __builtin_amdgcn_s_setprio(0);
      #pragma unroll
      for (int r = 0; r < 4; ++r) {
        float e  = __expf(s[r] * 0.125f);
        float st = s2[r] * 0.125f;
        float e2 = e * e;
        lsum[r] += e;
        int row = qrow + qd * 4 + r;
        lP[row * 72 + tj * 16 + ml] = f2b(e);
        lW[row * 72 + tj * 16 + ml] = f2b(e2 * st);
      }
    }
    // no barC: lP/lW producer lanes and consumer lanes are in the SAME wave
    // (rows [qrow, qrow+16) both sides); wave-level LDS ordering suffices.

    bf16x8 ap[2], aw[2], a3[2];
    #pragma unroll
    for (int ks = 0; ks < 2; ++ks) {
      ap[ks] = *(const bf16x8*)&lP[(qrow + ml) * 72 + ks * 32 + qd * 8];
      aw[ks] = *(const bf16x8*)&lW[(qrow + ml) * 72 + ks * 32 + qd * 8];
      #pragma unroll
      for (int e = 0; e < 8; ++e)
        a3[ks][e] = (__bf16)((float)ap[ks][e] * (float)aw[ks][e]);  // e^3*st
    }
    __builtin_amdgcn_s_setprio(1);
    #pragma unroll
    for (int tj = 0; tj < 4; ++tj) {
      bf16x8 vm0 = *(const bf16x8*)&lV[(tj * 16 + ml) * 72 + qd * 8];
      bf16x8 vm1 = *(const bf16x8*)&lV[(tj * 16 + ml) * 72 + 32 + qd * 8];
      bf16x8 vs0 = *(const bf16x8*)&lV[(64 + tj * 16 + ml) * 72 + qd * 8];
      bf16x8 vs1 = *(const bf16x8*)&lV[(64 + tj * 16 + ml) * 72 + 32 + qd * 8];
      accm[tj] = __builtin_amdgcn_mfma_f32_16x16x32_bf16(ap[0], vm0, accm[tj], 0, 0, 0);
      accm[tj] = __builtin_amdgcn_mfma_f32_16x16x32_bf16(ap[1], vm1, accm[tj], 0, 0, 0);
      acc2[tj] = __builtin_amdgcn_mfma_f32_16x16x32_bf16(aw[0], vs0, acc2[tj], 0, 0, 0);
      acc2[tj] = __builtin_amdgcn_mfma_f32_16x16x32_bf16(aw[1], vs1, acc2[tj], 0, 0, 0);
      acc3[tj] = __builtin_amdgcn_mfma_f32_16x16x32_bf16(a3[0], vs0, acc3[tj], 0, 0, 0);
      acc3[tj] = __builtin_amdgcn_mfma_f32_16x16x32_bf16(a3[1], vs1, acc3[tj], 0, 0, 0);
    }
    __builtin_amdgcn_s_setprio(0);
  }

  #pragma unroll
  for (int r = 0; r < 4; ++r) {
    float l = lsum[r];
    #pragma unroll
    for (int xo = 1; xo < 16; xo <<= 1) l += __shfl_xor(l, xo, 64);
    lsum[r] = l;
  }

  #pragma unroll
  for (int tj = 0; tj < 4; ++tj)
    #pragma unroll
    for (int r = 0; r < 4; ++r) {
      int row = i0 + qrow + qd * 4 + r;
      int col = h * 64 + tj * 16 + ml;
      size_t rowg = (size_t)b * 1024 + row;
      float il  = 1.0f / lsum[r];
      float il2 = il * il;
      float om = accm[tj][r] * il;
      float os = acc2[tj][r] * il2 - 2.0f * acc3[tj][r] * il2 * il;
      o_mu[rowg * 1024 + col] = f2b(om);
      size_t r2 = rowg * 2048 + col;
      a1sgo[r2] = f2b(fmaf(om, om, os));
      a1sgo[r2 + 1024] = f2b(os);
    }
}

// ---------------------------------------------------------------- launch
extern "C" void kernel_launch(void* const* d_in, const int* in_sizes, int n_in,
                              void* d_out, int out_size, void* d_ws, size_t ws_size,
                              hipStream_t stream)
{
  (void)in_sizes; (void)n_in; (void)out_size; (void)ws_size;
  const void* mu        = d_in[0];
  const void* sigma     = d_in[1];
  const void* gamma     = d_in[2];
  const void* beta      = d_in[3];
  const void* wqkv_mu   = d_in[4];
  const void* wqkv_sraw = d_in[5];
  const void* wout_mu   = d_in[6];
  const void* wout_sraw = d_in[7];

  u16* ws = (u16*)d_ws;
  const size_t R = 4096;  // B*N
  u16* mu_n   = ws;                        // R*1024, reused as mu_o
  u16* a1sg   = mu_n + R * 1024;           // R*2048 [A1|sgn], reused as a1sgo
  u16* wq_bf  = a1sg + R * 2048;           // 3072*1024
  u16* wqs2   = wq_bf + 3072 * 1024;       // 3072*2048 [Wsig|Wmu^2]
  u16* wo_bf  = wqs2 + 3072 * 2048;        // 1024*1024
  u16* wos2   = wo_bf + 1024 * 1024;       // 1024*2048
  u16* mu_qkv = wos2 + 1024 * 2048;        // R*3072
  u16* sg_qkv = mu_qkv + R * 3072;         // R*3072
  int* flag   = (int*)(sg_qkv + R * 3072);

  u16* mu_o  = mu_n;
  u16* a1sgo = a1sg;

  detect_kernel<<<1, 256, 0, stream>>>((const u16*)sigma, flag);

  // fused LN + weight prep (one dispatch)
  prep_kernel<<<8192, 256, 0, stream>>>(
      flag, mu, sigma, gamma, beta, mu_n, a1sg,
      wqkv_mu, wqkv_sraw, wq_bf, wqs2,
      wout_mu, wout_sraw, wo_bf, wos2);

  // merged QKV GEMMs (256^2 8-phase, 32x32 MFMA): sigma first (K=2048), then mu
  gemm8_pair_kernel<<<dim3(24, 16), 512, 0, stream>>>(
      a1sg, wqs2, 2048, sg_qkv,
      mu_n, wq_bf, 1024, mu_qkv,
      192, 3072);

  // fused single-pass attention (XCD-affine block decode, T5 setprio, 2 barriers/tile)
  attn_pass2f<<<dim3(512), 512, 0, stream>>>(mu_qkv, sg_qkv, mu_o, a1sgo);

  // merged output GEMMs (64x64 tiles, XCD-affine jobs, 2048 blocks = 8/CU)
  gemm_out_kernel<true><<<dim3(2048), 256, 0, stream>>>(
      mu_o, wo_bf, 1024, d_out, 0,
      a1sgo, wos2, 2048, d_out, R * 1024,
      1024, flag);
}

// Round 16
// 371.958 us; speedup vs baseline: 1.0392x; 1.0392x over previous
//
#include <hip/hip_runtime.h>

typedef unsigned short u16;
typedef unsigned int u32;
typedef __bf16 bf16x8 __attribute__((ext_vector_type(8)));
typedef float f32x4 __attribute__((ext_vector_type(4)));
typedef float f32x16 __attribute__((ext_vector_type(16)));

__device__ __forceinline__ float b2f(u16 u) { return __uint_as_float(((u32)u) << 16); }
__device__ __forceinline__ u16 f2b(float f) {
  u32 u = __float_as_uint(f);
  u += 0x7fffu + ((u >> 16) & 1u);   // round-to-nearest-even
  return (u16)(u >> 16);
}

// async global->LDS, 16B per lane; lds dest = wave-uniform base + lane*16
__device__ __forceinline__ void gll16(const u16* g, u16* l) {
  __builtin_amdgcn_global_load_lds(
      (const __attribute__((address_space(1))) void*)g,
      (__attribute__((address_space(3))) void*)l, 16, 0, 0);
}

// load 4 consecutive elements, dtype-polymorphic (uniform branch)
__device__ __forceinline__ float4 load4(const void* p, size_t idx, bool f32) {
  if (f32) return *(const float4*)((const float*)p + idx);
  ushort4 u = *(const ushort4*)((const u16*)p + idx);
  return make_float4(b2f(u.x), b2f(u.y), b2f(u.z), b2f(u.w));
}

#define SB __builtin_amdgcn_sched_barrier(0)
#define BARRIER do { SB; __builtin_amdgcn_s_barrier(); SB; } while (0)

// ---------------------------------------------------------------- dtype sniff (device-side, proven)
__global__ __launch_bounds__(256) void detect_kernel(const u16* __restrict__ sig,
                                                     int* __restrict__ flag) {
  __shared__ int cnt;
  if (threadIdx.x == 0) cnt = 0;
  __syncthreads();
  int c = 0;
  for (int i = threadIdx.x; i < 16384; i += 256) {
    u16 v = sig[i];
    c += ((v & 0x7F80u) == 0x7F80u) ? 1 : 0;
  }
  atomicAdd(&cnt, c);
  __syncthreads();
  if (threadIdx.x == 0) *flag = (cnt >= 8) ? 1 : 0;
}

// ---------------------------------------------------------------- prep (LN + weight prep, fused dispatch)
__global__ __launch_bounds__(256) void prep_kernel(
    const int* __restrict__ flag,
    const void* __restrict__ mu, const void* __restrict__ sigma,
    const void* __restrict__ gamma, const void* __restrict__ beta,
    u16* __restrict__ mu_n, u16* __restrict__ a1sg,
    const void* __restrict__ wq_mu, const void* __restrict__ wq_sraw,
    u16* __restrict__ q_bf, u16* __restrict__ q_s2,
    const void* __restrict__ wo_mu, const void* __restrict__ wo_sraw,
    u16* __restrict__ o_bf, u16* __restrict__ o_s2)
{
  __shared__ float ps[4], pq[4];
  const bool f32 = (*flag != 0);
  const int t = threadIdx.x;

  if (blockIdx.x < 4096) {
    const int wv = t >> 6, lane = t & 63;
    const size_t base = (size_t)blockIdx.x * 1024 + (size_t)t * 4;
    float4 xm = load4(mu, base, f32);
    float4 xs = load4(sigma, base, f32);
    float x0 = xm.x, x1 = xm.y, x2 = xm.z, x3 = xm.w;
    float s0 = xs.x, s1 = xs.y, s2 = xs.z, s3 = xs.w;

    float sv = x0 + x1 + x2 + x3;
    float qv = x0*x0 + x1*x1 + x2*x2 + x3*x3;
    #pragma unroll
    for (int off = 32; off > 0; off >>= 1) {
      sv += __shfl_xor(sv, off, 64);
      qv += __shfl_xor(qv, off, 64);
    }
    if (lane == 0) { ps[wv] = sv; pq[wv] = qv; }
    __syncthreads();
    float sum = ps[0] + ps[1] + ps[2] + ps[3];
    float ssq = pq[0] + pq[1] + pq[2] + pq[3];

    float mean = sum * (1.0f / 1024.0f);
    float var  = ssq * (1.0f / 1024.0f) - mean * mean;
    float inv  = 1.0f / sqrtf(var + 1e-5f);
    float inv2 = inv * inv;

    float4 g4 = load4(gamma, (size_t)t * 4, f32);
    float4 b4 = load4(beta, (size_t)t * 4, f32);

    float m0 = (x0 - mean) * inv * g4.x + b4.x;
    float m1 = (x1 - mean) * inv * g4.y + b4.y;
    float m2 = (x2 - mean) * inv * g4.z + b4.z;
    float m3 = (x3 - mean) * inv * g4.w + b4.w;
    float v0 = s0 * g4.x * g4.x * inv2;
    float v1 = s1 * g4.y * g4.y * inv2;
    float v2 = s2 * g4.z * g4.z * inv2;
    float v3 = s3 * g4.w * g4.w * inv2;

    ushort4 omu = { f2b(m0), f2b(m1), f2b(m2), f2b(m3) };
    ushort4 oa1 = { f2b(m0*m0 + v0), f2b(m1*m1 + v1), f2b(m2*m2 + v2), f2b(m3*m3 + v3) };
    ushort4 osg = { f2b(v0), f2b(v1), f2b(v2), f2b(v3) };
    *(ushort4*)(mu_n + base) = omu;
    size_t r2 = (size_t)blockIdx.x * 2048 + (size_t)t * 4;
    *(ushort4*)(a1sg + r2) = oa1;
    *(ushort4*)(a1sg + r2 + 1024) = osg;
  } else {
    const int nq = 3072 * 1024;
    size_t idx = ((size_t)(blockIdx.x - 4096) * 256 + t) * 4;
    const void *wmu, *wsr; u16 *obf, *os2;
    if (idx < (size_t)nq) { wmu = wq_mu; wsr = wq_sraw; obf = q_bf; os2 = q_s2; }
    else { idx -= nq; wmu = wo_mu; wsr = wo_sraw; obf = o_bf; os2 = o_s2; }
    int row = (int)(idx >> 10), k = (int)(idx & 1023);
    float4 m4 = load4(wmu, idx, f32);
    float4 s4 = load4(wsr, idx, f32);
    float m[4] = { m4.x, m4.y, m4.z, m4.w };
    float s[4] = { s4.x, s4.y, s4.z, s4.w };
    ushort4 ob, os, oq;
    u16* obp = (u16*)&ob; u16* osp = (u16*)&os; u16* oqp = (u16*)&oq;
    #pragma unroll
    for (int i = 0; i < 4; ++i) {
      float sp = (s[i] > 15.f) ? s[i] : log1pf(__expf(s[i]));
      obp[i] = f2b(m[i]);
      osp[i] = f2b(sp);
      oqp[i] = f2b(m[i] * m[i]);
    }
    *(ushort4*)(obf + idx) = ob;
    size_t r2 = (size_t)row * 2048 + k;
    *(ushort4*)(os2 + r2) = os;
    *(ushort4*)(os2 + r2 + 1024) = oq;
  }
}

// ---------------------------------------------------------------- out GEMM (64x64 tiles, drain, XCD-affine, 6 blocks/CU)
// Occupancy curve measured: 2->4 = -9us, 4->6 = -13us, 6->8 = +12us (VGPR
// squeeze). Optimum locked at (256,6). 16KB LDS, 2048 blocks.
template<bool DYN>
__global__ __launch_bounds__(256, 6) void gemm_out_kernel(
    const u16* __restrict__ A0, const u16* __restrict__ B0, int K0, void* C0, size_t ob0,
    const u16* __restrict__ A1, const u16* __restrict__ B1, int K1, void* C1, size_t ob1,
    int N, const int* __restrict__ flag)
{
  __shared__ u16 lA[64 * 64];
  __shared__ u16 lB[64 * 64];
  const int t = threadIdx.x;

  const int wgid = blockIdx.x;          // 2048
  const int xcd = wgid & 7;
  const int idx = wgid >> 3;            // 0..255 per XCD
  const u16 *A, *B; void* C; size_t obase; int K; int l;
  if (idx < 128) { A = A0; B = B0; K = K0; C = C0; obase = ob0; l = idx; }
  else           { A = A1; B = B1; K = K1; C = C1; obase = ob1; l = idx - 128; }
  const int by = xcd * 8 + (l >> 4);    // 0..63  (64 m-panels of 64 rows)
  const int bx = l & 15;                // 0..15  (16 n-tiles of 64 cols)
  const int n0 = bx * 64, m0 = by * 64;

  const int lane = t & 63, wave = t >> 6;
  const int wr = (wave >> 1) * 32, wc = (wave & 1) * 32;
  const int m31 = lane & 31, h5 = lane >> 5;
  const int mx = m31 & 7;

  const int srow = t >> 3;              // 0..31
  const int gseg = (t & 7) ^ (srow & 7);

  f32x16 acc;
  #pragma unroll
  for (int r = 0; r < 16; ++r) acc[r] = 0.f;

  for (int k0 = 0; k0 < K; k0 += 64) {
    __syncthreads();
    #pragma unroll
    for (int rep = 0; rep < 2; ++rep) {
      gll16(A + (size_t)(m0 + srow + rep * 32) * K + k0 + gseg * 8,
            lA + rep * 2048 + wave * 512);
      gll16(B + (size_t)(n0 + srow + rep * 32) * K + k0 + gseg * 8,
            lB + rep * 2048 + wave * 512);
    }
    __syncthreads();
    #pragma unroll
    for (int ks = 0; ks < 4; ++ks) {
      const int seg = ks * 2 + h5;
      bf16x8 af = *(const bf16x8*)&lA[(wr + m31) * 64 + (seg ^ mx) * 8];
      bf16x8 bfr = *(const bf16x8*)&lB[(wc + m31) * 64 + (seg ^ mx) * 8];
      acc = __builtin_amdgcn_mfma_f32_32x32x16_bf16(af, bfr, acc, 0, 0, 0);
    }
  }

  const bool of32 = DYN && (*flag != 0);
  {
    int colb = n0 + wc + m31;
    #pragma unroll
    for (int r = 0; r < 16; ++r) {
      int row = m0 + wr + (r & 3) + 8 * (r >> 2) + 4 * h5;
      float v = acc[r];
      size_t off = obase + (size_t)row * N + colb;
      if (DYN) {
        if (of32) ((float*)C)[off] = v;
        else      ((u16*)C)[off] = f2b(v);
      } else {
        ((u16*)C)[off] = f2b(v);
      }
    }
  }
}

// ---------------------------------------------------------------- paired GEMM (256^2, 8-phase counted-vmcnt, 32x32 MFMA)
// R3/R9-measured version (109.5 us on QKV).
__global__ __launch_bounds__(512, 2) void gemm8_pair_kernel(
    const u16* __restrict__ A0, const u16* __restrict__ B0, int K0, u16* __restrict__ C0,
    const u16* __restrict__ A1, const u16* __restrict__ B1, int K1, u16* __restrict__ C1,
    int split, int N)
{
  __shared__ u16 lA[2 * 256 * 64];
  __shared__ u16 lB[2 * 256 * 64];
  const int t = threadIdx.x;

  int wgid = blockIdx.y * 24 + blockIdx.x;     // 384 total; 192 per class
  int job;
  if (wgid < 192) job = (wgid & 7) * 24 + (wgid >> 3);
  else { int w2 = wgid - 192; job = 192 + (w2 & 7) * 24 + (w2 >> 3); }

  const u16 *A, *B; u16* C; int K, jb;
  if (job < split) { A = A0; B = B0; K = K0; C = C0; jb = job; }
  else { A = A1; B = B1; K = K1; C = C1; jb = job - split; }
  const int bm = jb & 15, bn = jb >> 4;        // 16 m-tiles x 12 n-tiles
  const int m0 = bm * 256, n0 = bn * 256;
  const int NT = K >> 6;

  const int lane = t & 63, wave = t >> 6;
  const int wm = wave >> 2, wn = wave & 3;
  const int m31 = lane & 31, h5 = lane >> 5, mx = m31 & 7;

  auto stg64 = [&](const u16* __restrict__ X, int row0, int k0, u16* ldsU) {
    int r = row0 + wave * 8 + (lane >> 3);
    int seg = (lane & 7) ^ ((lane >> 3) & 7);
    gll16(X + (size_t)r * K + k0 + seg * 8, ldsU + wave * 512);
  };

  const u16* rdA = lA + (wm * 128 + m31) * 64;
  const u16* rdB = lB + (wn * 64 + m31) * 64;

  f32x16 acc[4][2];
  #pragma unroll
  for (int i = 0; i < 4; ++i)
    #pragma unroll
    for (int j = 0; j < 2; ++j)
      #pragma unroll
      for (int r = 0; r < 16; ++r) acc[i][j][r] = 0.f;

  bf16x8 af[2][4];
  bf16x8 bf[2][4];

  #pragma unroll
  for (int u = 0; u < 4; ++u) stg64(A, m0 + u * 64, 0, lA + u * 4096);
  #pragma unroll
  for (int u = 0; u < 4; ++u) stg64(B, n0 + u * 64, 0, lB + u * 4096);
  if (NT > 1) {
    #pragma unroll
    for (int u = 0; u < 4; ++u) stg64(B, n0 + u * 64, 64, lB + 16384 + u * 4096);
  }
  SB;
  asm volatile("s_waitcnt vmcnt(4)" ::: "memory");
  BARRIER;

  for (int T = 0; T < NT; ++T) {
    const int bo  = (T & 1) * 16384;
    const int bon = bo ^ 16384;
    const int kn  = (T + 1) * 64;
    const int kn2 = (T + 2) * 64;

    // -------- P1
    #pragma unroll
    for (int mf = 0; mf < 2; ++mf)
      #pragma unroll
      for (int ks = 0; ks < 4; ++ks)
        af[mf][ks] = *(const bf16x8*)&rdA[bo + mf * 2048 + (((ks * 2 + h5)) ^ mx) * 8];
    #pragma unroll
    for (int ks = 0; ks < 4; ++ks)
      bf[0][ks] = *(const bf16x8*)&rdB[bo + (((ks * 2 + h5)) ^ mx) * 8];
    if (T + 1 < NT) {
      stg64(A, m0,      kn, lA + bon);
      stg64(A, m0 + 64, kn, lA + bon + 4096);
    }
    BARRIER;
    __builtin_amdgcn_s_setprio(1);
    #pragma unroll
    for (int mf = 0; mf < 2; ++mf)
      #pragma unroll
      for (int ks = 0; ks < 4; ++ks)
        acc[mf][0] = __builtin_amdgcn_mfma_f32_32x32x16_bf16(af[mf][ks], bf[0][ks], acc[mf][0], 0, 0, 0);
    __builtin_amdgcn_s_setprio(0);
    BARRIER;

    // -------- P2
    #pragma unroll
    for (int ks = 0; ks < 4; ++ks)
      bf[1][ks] = *(const bf16x8*)&rdB[bo + 2048 + (((ks * 2 + h5)) ^ mx) * 8];
    if (T + 1 < NT) {
      stg64(A, m0 + 128, kn, lA + bon + 8192);
      stg64(A, m0 + 192, kn, lA + bon + 12288);
    }
    BARRIER;
    __builtin_amdgcn_s_setprio(1);
    #pragma unroll
    for (int mf = 0; mf < 2; ++mf)
      #pragma unroll
      for (int ks = 0; ks < 4; ++ks)
        acc[mf][1] = __builtin_amdgcn_mfma_f32_32x32x16_bf16(af[mf][ks], bf[1][ks], acc[mf][1], 0, 0, 0);
    __builtin_amdgcn_s_setprio(0);
    BARRIER;

    // -------- P3
    #pragma unroll
    for (int mf = 0; mf < 2; ++mf)
      #pragma unroll
      for (int ks = 0; ks < 4; ++ks)
        af[mf][ks] = *(const bf16x8*)&rdA[bo + (2 + mf) * 2048 + (((ks * 2 + h5)) ^ mx) * 8];
    if (T + 2 < NT) {
      stg64(B, n0,      kn2, lB + bo);
      stg64(B, n0 + 64, kn2, lB + bo + 4096);
    }
    BARRIER;
    __builtin_amdgcn_s_setprio(1);
    #pragma unroll
    for (int mf = 0; mf < 2; ++mf)
      #pragma unroll
      for (int ks = 0; ks < 4; ++ks)
        acc[2 + mf][1] = __builtin_amdgcn_mfma_f32_32x32x16_bf16(af[mf][ks], bf[1][ks], acc[2 + mf][1], 0, 0, 0);
    __builtin_amdgcn_s_setprio(0);
    BARRIER;

    // -------- P4
    if (T + 2 < NT) {
      stg64(B, n0 + 128, kn2, lB + bo + 8192);
      stg64(B, n0 + 192, kn2, lB + bo + 12288);
    }
    BARRIER;
    __builtin_amdgcn_s_setprio(1);
    #pragma unroll
    for (int mf = 0; mf < 2; ++mf)
      #pragma unroll
      for (int ks = 0; ks < 4; ++ks)
        acc[2 + mf][0] = __builtin_amdgcn_mfma_f32_32x32x16_bf16(af[mf][ks], bf[0][ks], acc[2 + mf][0], 0, 0, 0);
    __builtin_amdgcn_s_setprio(0);
    SB;
    if (T + 2 < NT) asm volatile("s_waitcnt vmcnt(4)" ::: "memory");
    else            asm volatile("s_waitcnt vmcnt(0)" ::: "memory");
    BARRIER;
  }

  #pragma unroll
  for (int mf = 0; mf < 4; ++mf)
    #pragma unroll
    for (int nf = 0; nf < 2; ++nf) {
      int colb = n0 + wn * 64 + nf * 32 + m31;
      #pragma unroll
      for (int r = 0; r < 16; ++r) {
        int row = m0 + wm * 128 + mf * 32 + (r & 3) + 8 * (r >> 2) + 4 * h5;
        C[(size_t)row * N + colb] = f2b(acc[mf][nf][r]);
      }
    }
}

// ---------------------------------------------------------------- fused attention (single pass, XCD-affine, T5 setprio)
// R11/R12-measured 111us body (2 barriers/tile, in-register a3 = ap (.) aw).
__global__ __launch_bounds__(512, 4) void attn_pass2f(
    const u16* __restrict__ qkv_mu, const u16* __restrict__ qkv_sg,
    u16* __restrict__ o_mu, u16* __restrict__ a1sgo)
{
  __shared__ u16 lKW[128 * 72];   // K-mu | K-sg
  __shared__ u16 lV[128 * 72];    // V-mu | V-sg (transposed)
  __shared__ u16 lP[128 * 72];    // e (unnormalized p)
  __shared__ u16 lW[128 * 72];    // e^2 * ss~

  const int t = threadIdx.x;
  const int wv = t >> 6, lane = t & 63;
  const int ml = lane & 15, qd = lane >> 4;
  const int bid = blockIdx.x;
  const int ib = (bid >> 3) & 7;
  const int bh = (bid & 7) + ((bid >> 6) << 3);
  const int b = bh >> 4, h = bh & 15;
  const size_t rowbase = (size_t)b * 1024 * 3072;
  const int i0 = ib * 128;
  const int qcol = h * 64, kcol = 1024 + h * 64, vcol = 2048 + h * 64;
  const int qrow = wv * 16;

  bf16x8 aQm[2], aQs[2];
  #pragma unroll
  for (int ks = 0; ks < 2; ++ks) {
    size_t ga = rowbase + (size_t)(i0 + qrow + ml) * 3072 + qcol + ks * 32 + qd * 8;
    aQm[ks] = *(const bf16x8*)(qkv_mu + ga);
    aQs[ks] = *(const bf16x8*)(qkv_sg + ga);
  }

  float lsum[4] = {0.f, 0.f, 0.f, 0.f};
  f32x4 accm[4], acc2[4], acc3[4];
  #pragma unroll
  for (int tj = 0; tj < 4; ++tj) {
    accm[tj] = (f32x4){0.f, 0.f, 0.f, 0.f};
    acc2[tj] = (f32x4){0.f, 0.f, 0.f, 0.f};
    acc3[tj] = (f32x4){0.f, 0.f, 0.f, 0.f};
  }

  for (int j0 = 0; j0 < 1024; j0 += 64) {
    __syncthreads();   // barA: prev-tile PV reads done before restaging
    #pragma unroll
    for (int rep = 0; rep < 2; ++rep) {
      int c = t + rep * 512;
      int row = c >> 3, seg = c & 7;
      const u16* src = (row < 64) ? qkv_mu : qkv_sg;
      int rr = row & 63;
      *(uint4*)&lKW[row * 72 + seg * 8] =
          *(const uint4*)(src + rowbase + (size_t)(j0 + rr) * 3072 + kcol + seg * 8);
    }
    {
      int buf = t >> 8, rem = t & 255;
      int db = rem >> 4, tb = rem & 15;
      const u16* src = buf ? qkv_sg : qkv_mu;
      ushort4 vals[4];
      #pragma unroll
      for (int i = 0; i < 4; ++i)
        vals[i] = *(const ushort4*)(src + rowbase + (size_t)(j0 + tb * 4 + i) * 3072 + vcol + db * 4);
      #pragma unroll
      for (int k = 0; k < 4; ++k) {
        ushort4 o;
        u16* op = (u16*)&o;
        const u16* v0 = (const u16*)&vals[0];
        const u16* v1 = (const u16*)&vals[1];
        const u16* v2 = (const u16*)&vals[2];
        const u16* v3 = (const u16*)&vals[3];
        op[0] = v0[k]; op[1] = v1[k]; op[2] = v2[k]; op[3] = v3[k];
        *(ushort4*)&lV[(buf * 64 + db * 4 + k) * 72 + tb * 4] = o;
      }
    }
    __syncthreads();   // barB: staging visible

    #pragma unroll
    for (int tj = 0; tj < 4; ++tj) {
      bf16x8 bm0 = *(const bf16x8*)&lKW[(tj * 16 + ml) * 72 + qd * 8];
      bf16x8 bm1 = *(const bf16x8*)&lKW[(tj * 16 + ml) * 72 + 32 + qd * 8];
      bf16x8 bs0 = *(const bf16x8*)&lKW[(64 + tj * 16 + ml) * 72 + qd * 8];
      bf16x8 bs1 = *(const bf16x8*)&lKW[(64 + tj * 16 + ml) * 72 + 32 + qd * 8];
      __builtin_amdgcn_s_setprio(1);
      f32x4 s = (f32x4){0.f, 0.f, 0.f, 0.f};
      s = __builtin_amdgcn_mfma_f32_16x16x32_bf16(aQm[0], bm0, s, 0, 0, 0);
      s = __builtin_amdgcn_mfma_f32_16x16x32_bf16(aQm[1], bm1, s, 0, 0, 0);
      f32x4 s2 = (f32x4){0.f, 0.f, 0.f, 0.f};
      s2 = __builtin_amdgcn_mfma_f32_16x16x32_bf16(aQs[0], bs0, s2, 0, 0, 0);
      s2 = __builtin_amdgcn_mfma_f32_16x16x32_bf16(aQs[1], bs1, s2, 0, 0, 0);
      __builtin_amdgcn_s_setprio(0);
      #pragma unroll
      for (int r = 0; r < 4; ++r) {
        float e  = __expf(s[r] * 0.125f);
        float st = s2[r] * 0.125f;
        float e2 = e * e;
        lsum[r] += e;
        int row = qrow + qd * 4 + r;
        lP[row * 72 + tj * 16 + ml] = f2b(e);
        lW[row * 72 + tj * 16 + ml] = f2b(e2 * st);
      }
    }
    // no barC: lP/lW producer lanes and consumer lanes are in the SAME wave
    // (rows [qrow, qrow+16) both sides); wave-level LDS ordering suffices.

    bf16x8 ap[2], aw[2], a3[2];
    #pragma unroll
    for (int ks = 0; ks < 2; ++ks) {
      ap[ks] = *(const bf16x8*)&lP[(qrow + ml) * 72 + ks * 32 + qd * 8];
      aw[ks] = *(const bf16x8*)&lW[(qrow + ml) * 72 + ks * 32 + qd * 8];
      #pragma unroll
      for (int e = 0; e < 8; ++e)
        a3[ks][e] = (__bf16)((float)ap[ks][e] * (float)aw[ks][e]);  // e^3*st
    }
    __builtin_amdgcn_s_setprio(1);
    #pragma unroll
    for (int tj = 0; tj < 4; ++tj) {
      bf16x8 vm0 = *(const bf16x8*)&lV[(tj * 16 + ml) * 72 + qd * 8];
      bf16x8 vm1 = *(const bf16x8*)&lV[(tj * 16 + ml) * 72 + 32 + qd * 8];
      bf16x8 vs0 = *(const bf16x8*)&lV[(64 + tj * 16 + ml) * 72 + qd * 8];
      bf16x8 vs1 = *(const bf16x8*)&lV[(64 + tj * 16 + ml) * 72 + 32 + qd * 8];
      accm[tj] = __builtin_amdgcn_mfma_f32_16x16x32_bf16(ap[0], vm0, accm[tj], 0, 0, 0);
      accm[tj] = __builtin_amdgcn_mfma_f32_16x16x32_bf16(ap[1], vm1, accm[tj], 0, 0, 0);
      acc2[tj] = __builtin_amdgcn_mfma_f32_16x16x32_bf16(aw[0], vs0, acc2[tj], 0, 0, 0);
      acc2[tj] = __builtin_amdgcn_mfma_f32_16x16x32_bf16(aw[1], vs1, acc2[tj], 0, 0, 0);
      acc3[tj] = __builtin_amdgcn_mfma_f32_16x16x32_bf16(a3[0], vs0, acc3[tj], 0, 0, 0);
      acc3[tj] = __builtin_amdgcn_mfma_f32_16x16x32_bf16(a3[1], vs1, acc3[tj], 0, 0, 0);
    }
    __builtin_amdgcn_s_setprio(0);
  }

  #pragma unroll
  for (int r = 0; r < 4; ++r) {
    float l = lsum[r];
    #pragma unroll
    for (int xo = 1; xo < 16; xo <<= 1) l += __shfl_xor(l, xo, 64);
    lsum[r] = l;
  }

  #pragma unroll
  for (int tj = 0; tj < 4; ++tj)
    #pragma unroll
    for (int r = 0; r < 4; ++r) {
      int row = i0 + qrow + qd * 4 + r;
      int col = h * 64 + tj * 16 + ml;
      size_t rowg = (size_t)b * 1024 + row;
      float il  = 1.0f / lsum[r];
      float il2 = il * il;
      float om = accm[tj][r] * il;
      float os = acc2[tj][r] * il2 - 2.0f * acc3[tj][r] * il2 * il;
      o_mu[rowg * 1024 + col] = f2b(om);
      size_t r2 = rowg * 2048 + col;
      a1sgo[r2] = f2b(fmaf(om, om, os));
      a1sgo[r2 + 1024] = f2b(os);
    }
}

// ---------------------------------------------------------------- launch
extern "C" void kernel_launch(void* const* d_in, const int* in_sizes, int n_in,
                              void* d_out, int out_size, void* d_ws, size_t ws_size,
                              hipStream_t stream)
{
  (void)in_sizes; (void)n_in; (void)out_size; (void)ws_size;
  const void* mu        = d_in[0];
  const void* sigma     = d_in[1];
  const void* gamma     = d_in[2];
  const void* beta      = d_in[3];
  const void* wqkv_mu   = d_in[4];
  const void* wqkv_sraw = d_in[5];
  const void* wout_mu   = d_in[6];
  const void* wout_sraw = d_in[7];

  u16* ws = (u16*)d_ws;
  const size_t R = 4096;  // B*N
  u16* mu_n   = ws;                        // R*1024, reused as mu_o
  u16* a1sg   = mu_n + R * 1024;           // R*2048 [A1|sgn], reused as a1sgo
  u16* wq_bf  = a1sg + R * 2048;           // 3072*1024
  u16* wqs2   = wq_bf + 3072 * 1024;       // 3072*2048 [Wsig|Wmu^2]
  u16* wo_bf  = wqs2 + 3072 * 2048;        // 1024*1024
  u16* wos2   = wo_bf + 1024 * 1024;       // 1024*2048
  u16* mu_qkv = wos2 + 1024 * 2048;        // R*3072
  u16* sg_qkv = mu_qkv + R * 3072;         // R*3072
  int* flag   = (int*)(sg_qkv + R * 3072);

  u16* mu_o  = mu_n;
  u16* a1sgo = a1sg;

  detect_kernel<<<1, 256, 0, stream>>>((const u16*)sigma, flag);

  // fused LN + weight prep (one dispatch)
  prep_kernel<<<8192, 256, 0, stream>>>(
      flag, mu, sigma, gamma, beta, mu_n, a1sg,
      wqkv_mu, wqkv_sraw, wq_bf, wqs2,
      wout_mu, wout_sraw, wo_bf, wos2);

  // merged QKV GEMMs (256^2 8-phase, 32x32 MFMA): sigma first (K=2048), then mu
  gemm8_pair_kernel<<<dim3(24, 16), 512, 0, stream>>>(
      a1sg, wqs2, 2048, sg_qkv,
      mu_n, wq_bf, 1024, mu_qkv,
      192, 3072);

  // fused single-pass attention (XCD-affine block decode, T5 setprio, 2 barriers/tile)
  attn_pass2f<<<dim3(512), 512, 0, stream>>>(mu_qkv, sg_qkv, mu_o, a1sgo);

  // merged output GEMMs (64x64 tiles, XCD-affine jobs, 2048 blocks = 6/CU)
  gemm_out_kernel<true><<<dim3(2048), 256, 0, stream>>>(
      mu_o, wo_bf, 1024, d_out, 0,
      a1sgo, wos2, 2048, d_out, R * 1024,
      1024, flag);
}